// Round 1
// baseline (292.553 us; speedup 1.0000x reference)
//
#include <hip/hip_runtime.h>
#include <hip/hip_bf16.h>

#define IN_FT  128
#define OUT_FT 32
#define GEMM_ROWS 64     // rows per block
#define PITCH  132       // 128 + 4: breaks stride-128 bank aliasing, keeps 16B align

// -------------------- support = seq @ weight --------------------
// block = 256 threads; each block computes GEMM_ROWS rows of support.
// thread = 2 rows x 4 cols, k-vectorized by 4 (float4 LDS reads).
__global__ __launch_bounds__(256) void gcn_gemm(const float* __restrict__ seq,
                                                const float* __restrict__ w,
                                                float* __restrict__ sup,
                                                int n) {
    __shared__ __align__(16) float lw[IN_FT * OUT_FT];   // 16 KB
    __shared__ __align__(16) float ls[GEMM_ROWS * PITCH]; // ~33.8 KB

    const int tid = threadIdx.x;
    // load weight (4096 floats = 1024 float4)
    for (int i = tid; i < (IN_FT * OUT_FT) / 4; i += 256)
        ((float4*)lw)[i] = ((const float4*)w)[i];

    const int base = blockIdx.x * GEMM_ROWS;
    // load seq tile: 64 rows x 32 float4 = 2048 float4
    for (int i = tid; i < GEMM_ROWS * (IN_FT / 4); i += 256) {
        int r  = i >> 5;        // i / 32
        int kc = i & 31;        // float4 index within row
        int row = base + r;
        float4 v = make_float4(0.f, 0.f, 0.f, 0.f);
        if (row < n)
            v = ((const float4*)(seq + (size_t)row * IN_FT))[kc];
        *(float4*)&ls[r * PITCH + kc * 4] = v;
    }
    __syncthreads();

    const int cg = (tid & 7) * 4;   // col start: 0,4,...,28
    const int rp = tid >> 3;        // 0..31 -> rows 2rp, 2rp+1
    const int r0 = rp * 2, r1 = r0 + 1;

    float4 acc0 = make_float4(0.f, 0.f, 0.f, 0.f);
    float4 acc1 = make_float4(0.f, 0.f, 0.f, 0.f);

#define FMA4(acc, s, wv) \
    acc.x = fmaf((s), (wv).x, acc.x); \
    acc.y = fmaf((s), (wv).y, acc.y); \
    acc.z = fmaf((s), (wv).z, acc.z); \
    acc.w = fmaf((s), (wv).w, acc.w);

    for (int k = 0; k < IN_FT; k += 4) {
        float4 s0 = *(const float4*)&ls[r0 * PITCH + k];
        float4 s1 = *(const float4*)&ls[r1 * PITCH + k];
        float4 w0 = *(const float4*)&lw[(k + 0) * OUT_FT + cg];
        float4 w1 = *(const float4*)&lw[(k + 1) * OUT_FT + cg];
        float4 w2 = *(const float4*)&lw[(k + 2) * OUT_FT + cg];
        float4 w3 = *(const float4*)&lw[(k + 3) * OUT_FT + cg];
        FMA4(acc0, s0.x, w0); FMA4(acc0, s0.y, w1);
        FMA4(acc0, s0.z, w2); FMA4(acc0, s0.w, w3);
        FMA4(acc1, s1.x, w0); FMA4(acc1, s1.y, w1);
        FMA4(acc1, s1.z, w2); FMA4(acc1, s1.w, w3);
    }
#undef FMA4

    int row0 = base + r0;
    if (row0 < n) *(float4*)&sup[(size_t)row0 * OUT_FT + cg] = acc0;
    int row1 = base + r1;
    if (row1 < n) *(float4*)&sup[(size_t)row1 * OUT_FT + cg] = acc1;
}

// -------------------- out[row] += val * support[col] --------------------
// one thread per (edge, col): coalesced 128B gather per edge, fp32 atomics out.
__global__ __launch_bounds__(256) void gcn_scatter(const int* __restrict__ erow,
                                                   const int* __restrict__ ecol,
                                                   const float* __restrict__ eval,
                                                   const float* __restrict__ sup,
                                                   float* __restrict__ out,
                                                   int n_edges) {
    long long g = (long long)blockIdx.x * 256 + threadIdx.x;
    int e = (int)(g >> 5);
    int c = (int)(g & 31);
    if (e >= n_edges) return;
    int r  = erow[e];
    int cl = ecol[e];
    float v = eval[e];
    float m = v * sup[(size_t)cl * OUT_FT + c];
    atomicAdd(out + (size_t)r * OUT_FT + c, m);
}

// -------------------- relu in place --------------------
__global__ __launch_bounds__(256) void gcn_relu(float4* __restrict__ out, int n4) {
    int i = blockIdx.x * 256 + threadIdx.x;
    if (i < n4) {
        float4 v = out[i];
        v.x = fmaxf(v.x, 0.f);
        v.y = fmaxf(v.y, 0.f);
        v.z = fmaxf(v.z, 0.f);
        v.w = fmaxf(v.w, 0.f);
        out[i] = v;
    }
}

extern "C" void kernel_launch(void* const* d_in, const int* in_sizes, int n_in,
                              void* d_out, int out_size, void* d_ws, size_t ws_size,
                              hipStream_t stream) {
    const float* seq  = (const float*)d_in[0];
    const float* w    = (const float*)d_in[1];
    const int*   erow = (const int*)d_in[2];
    const int*   ecol = (const int*)d_in[3];
    const float* eval = (const float*)d_in[4];
    float* out = (float*)d_out;
    float* sup = (float*)d_ws;   // n_nodes * 32 floats = 12.8 MB

    const int n_nodes = in_sizes[0] / IN_FT;
    const int n_edges = in_sizes[2];

    // out accumulator must start at zero (harness poisons with 0xAA)
    hipMemsetAsync(d_out, 0, (size_t)out_size * sizeof(float), stream);

    // 1) support = seq @ weight
    int gemm_blocks = (n_nodes + GEMM_ROWS - 1) / GEMM_ROWS;
    gcn_gemm<<<gemm_blocks, 256, 0, stream>>>(seq, w, sup, n_nodes);

    // 2) scatter-add messages
    long long work = (long long)n_edges * OUT_FT;
    int sc_blocks = (int)((work + 255) / 256);
    gcn_scatter<<<sc_blocks, 256, 0, stream>>>(erow, ecol, eval, sup, out, n_edges);

    // 3) relu
    int n4 = out_size / 4;
    gcn_relu<<<(n4 + 255) / 256, 256, 0, stream>>>((float4*)out, n4);
}